// Round 3
// baseline (124.980 us; speedup 1.0000x reference)
//
#include <hip/hip_runtime.h>

// predict/target: fp32, shape (64, 3, 17, 4096)
// loss = sum((t-p)^2 * w[c]) / (bs*actionlen*seqlen),  w = {1, 1, 75825}
//
// Single kernel: fully-unrolled (8 iters, no bounds check) float4 reduction;
// each block atomicAdds its scaled partial into d_out[0] (zeroed via
// hipMemsetAsync, which is graph-capturable). Removes the 2nd launch.

#define BLOCK_SIZE 256
#define ITERS 8
#define VEC_PER_CHAN 17408   // (17*4096)/4 : float4-groups per channel segment
#define W2 75825.0f          // MAXLEN

__global__ __launch_bounds__(BLOCK_SIZE) void pm_mse_onepass(
    const float4* __restrict__ p, const float4* __restrict__ t,
    float* __restrict__ out, float scale, int stride /* total threads */) {
    const int tid = blockIdx.x * BLOCK_SIZE + threadIdx.x;

    float4 a[ITERS], b[ITERS];
    #pragma unroll
    for (int k = 0; k < ITERS; ++k) {
        int i = tid + k * stride;
        a[k] = p[i];
        b[k] = t[i];
    }
    float acc = 0.0f;
    #pragma unroll
    for (int k = 0; k < ITERS; ++k) {
        int i = tid + k * stride;
        float dx = b[k].x - a[k].x;
        float dy = b[k].y - a[k].y;
        float dz = b[k].z - a[k].z;
        float dw = b[k].w - a[k].w;
        float s = dx * dx + dy * dy + dz * dz + dw * dw;
        int c = (i / VEC_PER_CHAN) % 3;   // vec4 never straddles a channel
        acc += (c == 2) ? s * W2 : s;
    }

    // wave reduce (64 lanes)
    for (int off = 32; off > 0; off >>= 1)
        acc += __shfl_down(acc, off, 64);
    __shared__ float smem[BLOCK_SIZE / 64];
    const int lane = threadIdx.x & 63;
    const int wid = threadIdx.x >> 6;
    if (lane == 0) smem[wid] = acc;
    __syncthreads();
    if (threadIdx.x == 0) {
        float s = 0.0f;
        #pragma unroll
        for (int w = 0; w < BLOCK_SIZE / 64; ++w) s += smem[w];
        atomicAdd(out, s * scale);   // device-scope, one per block
    }
}

// generic fallback (any n4): grid-stride with bounds check
__global__ __launch_bounds__(BLOCK_SIZE) void pm_mse_onepass_generic(
    const float4* __restrict__ p, const float4* __restrict__ t,
    float* __restrict__ out, float scale, int n4) {
    float acc = 0.0f;
    const int stride = gridDim.x * blockDim.x;
    for (int i = blockIdx.x * blockDim.x + threadIdx.x; i < n4; i += stride) {
        float4 a = p[i];
        float4 b = t[i];
        float dx = b.x - a.x;
        float dy = b.y - a.y;
        float dz = b.z - a.z;
        float dw = b.w - a.w;
        float s = dx * dx + dy * dy + dz * dz + dw * dw;
        int c = (i / VEC_PER_CHAN) % 3;
        acc += (c == 2) ? s * W2 : s;
    }
    for (int off = 32; off > 0; off >>= 1)
        acc += __shfl_down(acc, off, 64);
    __shared__ float smem[BLOCK_SIZE / 64];
    const int lane = threadIdx.x & 63;
    const int wid = threadIdx.x >> 6;
    if (lane == 0) smem[wid] = acc;
    __syncthreads();
    if (threadIdx.x == 0) {
        float s = 0.0f;
        #pragma unroll
        for (int w = 0; w < BLOCK_SIZE / 64; ++w) s += smem[w];
        atomicAdd(out, s * scale);
    }
}

extern "C" void kernel_launch(void* const* d_in, const int* in_sizes, int n_in,
                              void* d_out, int out_size, void* d_ws, size_t ws_size,
                              hipStream_t stream) {
    const float* predict = (const float*)d_in[0];
    const float* target  = (const float*)d_in[1];
    float* out = (float*)d_out;

    const int n = in_sizes[0];      // 64*3*17*4096 = 13,369,344
    const int n4 = n / 4;           // 3,342,336 = 256 * 8 * 1632
    const float scale = 3.0f / (float)n;  // divisor = n / ddim

    hipMemsetAsync(out, 0, sizeof(float), stream);  // graph-capturable

    const int chunk = BLOCK_SIZE * ITERS;
    if (n4 % chunk == 0) {
        const int blocks = n4 / chunk;               // 1632
        const int stride = blocks * BLOCK_SIZE;      // 417,792
        pm_mse_onepass<<<blocks, BLOCK_SIZE, 0, stream>>>(
            (const float4*)predict, (const float4*)target, out, scale, stride);
    } else {
        int blocks = (n4 + BLOCK_SIZE - 1) / BLOCK_SIZE;
        if (blocks > 2048) blocks = 2048;
        pm_mse_onepass_generic<<<blocks, BLOCK_SIZE, 0, stream>>>(
            (const float4*)predict, (const float4*)target, out, scale, n4);
    }
}